// Round 3
// baseline (44.335 us; speedup 1.0000x reference)
//
#include <hip/hip_runtime.h>
#include <math.h>

#define HW    524288u     // 512*1024  (= 2^19)
#define NPIX  2097152u    // 4*512*1024
#define NCH   19
#define NC    12
#define BLK   256
#define GRID  1024
#define ITERS 4           // NPIX / (2*BLK*GRID)

// ---- per-pixel: 19 logits -> (sum of 12 plane values squared, argmax plane)
__device__ __forceinline__ void pixel_eval(const float p[NCH], float& s2, int& pred) {
    float o[NC];
    // IDS_MAPPING groups: raw-logit sums
    o[2] = p[2] + p[3] + p[4];
    o[4] = p[6] + p[7];
    o[5] = p[8] + p[9] + p[10];
    o[8] = p[13] + p[14] + p[15];
    // softmax without max-subtract: inputs ~ N(0,1), |p| < ~6 -> expf safe in f32
    float Z = 0.f;
    #pragma unroll
    for (int c = 0; c < NCH; ++c) {
        float t = __expf(p[c]);
        Z += t;
        if (c == 0)  o[0]  = t;
        if (c == 1)  o[1]  = t;
        if (c == 5)  o[3]  = t;
        if (c == 11) o[6]  = t;
        if (c == 12) o[7]  = t;
        if (c == 16) o[9]  = t;
        if (c == 17) o[10] = t;
        if (c == 18) o[11] = t;
    }
    float invZ = __builtin_amdgcn_rcpf(Z);   // ~1e-7 rel err, plenty for 6.6e-3 abs threshold
    o[0] *= invZ; o[1] *= invZ; o[3]  *= invZ; o[6]  *= invZ;
    o[7] *= invZ; o[9] *= invZ; o[10] *= invZ; o[11] *= invZ;

    float best = o[0]; int bi = 0; float acc = o[0] * o[0];
    #pragma unroll
    for (int k = 1; k < NC; ++k) {
        acc = fmaf(o[k], o[k], acc);
        if (o[k] > best) { best = o[k]; bi = k; }  // strict > keeps first-max (jnp.argmax) semantics
    }
    s2 = acc; pred = bi;
}

// ---- pass 1: per-class count + per-class sum of s2
__global__ __launch_bounds__(BLK, 4) void msiwc_pass1(const float* __restrict__ x,
                                                      float* __restrict__ ws) {
    float cnt[NC], sum[NC];
    #pragma unroll
    for (int k = 0; k < NC; ++k) { cnt[k] = 0.f; sum[k] = 0.f; }

    #pragma unroll 1   // do NOT hoist all iterations' loads (register blowup)
    for (unsigned it = 0; it < ITERS; ++it) {
        unsigned pair = it * (BLK * GRID) + blockIdx.x * BLK + threadIdx.x;
        unsigned p0 = pair * 2u;
        unsigned n  = p0 >> 19;          // pixel / (H*W)
        unsigned hw = p0 & (HW - 1u);
        const float* base = x + (size_t)n * NCH * HW + hw;

        float2 v[NCH];                   // 38 VGPRs payload -> ~100 peak live, 4 waves/SIMD
        #pragma unroll
        for (int c = 0; c < NCH; ++c)
            v[c] = *reinterpret_cast<const float2*>(base + (size_t)c * HW);

        #pragma unroll
        for (int j = 0; j < 2; ++j) {
            float pv[NCH];
            #pragma unroll
            for (int c = 0; c < NCH; ++c) pv[c] = j ? v[c].y : v[c].x;  // folds after unroll
            float s2; int pred;
            pixel_eval(pv, s2, pred);
            #pragma unroll
            for (int k = 0; k < NC; ++k) {
                bool h = (pred == k);
                cnt[k] += h ? 1.f : 0.f;
                sum[k] += h ? s2  : 0.f;
            }
        }
    }

    // 64-lane butterfly reduce per class (replaces serial 256-deep LDS column sums)
    #pragma unroll
    for (int k = 0; k < NC; ++k) {
        #pragma unroll
        for (int off = 32; off > 0; off >>= 1) {
            cnt[k] += __shfl_xor(cnt[k], off, 64);
            sum[k] += __shfl_xor(sum[k], off, 64);
        }
    }

    __shared__ float s_red[BLK / 64][2 * NC];
    unsigned lane = threadIdx.x & 63u, wid = threadIdx.x >> 6;
    if (lane == 0) {
        #pragma unroll
        for (int k = 0; k < NC; ++k) {
            s_red[wid][k]      = cnt[k];
            s_red[wid][NC + k] = sum[k];
        }
    }
    __syncthreads();
    if (threadIdx.x < 2 * NC) {
        float a = 0.f;
        #pragma unroll
        for (int w = 0; w < BLK / 64; ++w) a += s_red[w][threadIdx.x];
        atomicAdd(&ws[threadIdx.x], a);   // 1024 blocks x 24 addrs: trivial contention
    }
}

// ---- pass 2: weights from histogram, final scalar
__global__ void msiwc_pass2(const float* __restrict__ ws, float* __restrict__ out) {
    __shared__ float terms[NC];
    int k = threadIdx.x;
    if (k < NC) {
        double hist = (double)ws[k];
        double w = pow(hist, 0.2) * pow((double)NPIX, 0.8);
        if (w < 1.0) w = 1.0;
        terms[k] = (float)((double)ws[NC + k] / w);
    }
    __syncthreads();
    if (k == 0) {
        float tot = 0.f;
        #pragma unroll
        for (int i = 0; i < NC; ++i) tot += terms[i];
        out[0] = -tot / 48.0f;   // N*C = 4*12
    }
}

extern "C" void kernel_launch(void* const* d_in, const int* in_sizes, int n_in,
                              void* d_out, int out_size, void* d_ws, size_t ws_size,
                              hipStream_t stream) {
    const float* x = (const float*)d_in[0];
    float* ws = (float*)d_ws;

    // ws is poisoned once (0xAA) and NOT re-poisoned between graph replays:
    // zero the 24 accumulators every call.
    hipMemsetAsync(ws, 0, 2 * NC * sizeof(float), stream);

    msiwc_pass1<<<GRID, BLK, 0, stream>>>(x, ws);
    msiwc_pass2<<<1, 64, 0, stream>>>(ws, (float*)d_out);
}